// Round 1
// baseline (104.080 us; speedup 1.0000x reference)
//
#include <hip/hip_runtime.h>
#include <math.h>

#define B 512
#define D 256
#define MARGIN 0.3f
#define UW 0.05f
#define MIN_U 1e-6f
#define MAX_U 1.0f
#define EPS 1e-8f

// acc[0] = sum of per_triplet over valid anchors
// acc[1] = n_valid (as float)
// acc[2] = sum of clipped u over all B*D elements
__global__ __launch_bounds__(256) void triplet_main(const float* __restrict__ emb,
                                                    const float* __restrict__ unc,
                                                    const int* __restrict__ labels,
                                                    float* __restrict__ acc) {
    const int i = blockIdx.x;
    const int t = threadIdx.x;

    __shared__ float ei[D];      // anchor embedding row
    __shared__ float wi[D];      // clipped u_i^2
    __shared__ float rv[256];    // reduction: pos value / later sp
    __shared__ int   ri[256];    // reduction: pos index
    __shared__ float rv2[256];   // reduction: neg value / later sn
    __shared__ int   ri2[256];   // reduction: neg index
    __shared__ float ru[256];    // reduction: u row sum
    __shared__ int   s_jp, s_jn;
    __shared__ float s_dp, s_dn;
    __shared__ int   s_valid;

    // ---- load anchor row, clip uncertainties ----
    float e = emb[(size_t)i * D + t];
    float u = unc[(size_t)i * D + t];
    u = fminf(fmaxf(u, MIN_U), MAX_U);
    if (!isfinite(u)) u = MIN_U;
    ei[t] = e;
    wi[t] = u * u;
    __syncthreads();

    const int lab_i = labels[i];
    const float4* ei4 = reinterpret_cast<const float4*>(ei);

    // ---- distances for j = t and j = t+256 ----
    const int jA = t;
    const int jB = t + 256;
    const float4* rowA = reinterpret_cast<const float4*>(emb + (size_t)jA * D);
    const float4* rowB = reinterpret_cast<const float4*>(emb + (size_t)jB * D);
    float d2a = 0.f, d2b = 0.f;
#pragma unroll 8
    for (int k = 0; k < D / 4; ++k) {
        float4 a = ei4[k];
        float4 x = rowA[k];
        float4 y = rowB[k];
        float dx;
        dx = a.x - x.x; d2a = fmaf(dx, dx, d2a);
        dx = a.y - x.y; d2a = fmaf(dx, dx, d2a);
        dx = a.z - x.z; d2a = fmaf(dx, dx, d2a);
        dx = a.w - x.w; d2a = fmaf(dx, dx, d2a);
        dx = a.x - y.x; d2b = fmaf(dx, dx, d2b);
        dx = a.y - y.y; d2b = fmaf(dx, dx, d2b);
        dx = a.z - y.z; d2b = fmaf(dx, dx, d2b);
        dx = a.w - y.w; d2b = fmaf(dx, dx, d2b);
    }
    float distA = sqrtf(d2a) + EPS;
    float distB = sqrtf(d2b) + EPS;

    // ---- masked candidates (mirror reference: masked value, argmax/argmin
    //      with first-index tie-break) ----
    const int labA = labels[jA];
    const int labB = labels[jB];
    bool posA = (labA == lab_i) && (jA != i);
    bool posB = (labB == lab_i) && (jB != i);
    bool negA = (labA != lab_i);
    bool negB = (labB != lab_i);

    float pvA = posA ? distA : -1e30f;
    float pvB = posB ? distB : -1e30f;
    float nvA = negA ? distA : 1e30f;
    float nvB = negB ? distB : 1e30f;

    // combine the two j's this thread owns (jA < jB, so > / < keeps first idx)
    float best_pv = pvA; int best_pj = jA;
    if (pvB > best_pv) { best_pv = pvB; best_pj = jB; }
    float best_nv = nvA; int best_nj = jA;
    if (nvB < best_nv) { best_nv = nvB; best_nj = jB; }

    rv[t] = best_pv; ri[t] = best_pj;
    rv2[t] = best_nv; ri2[t] = best_nj;
    __syncthreads();

    for (int s = 128; s > 0; s >>= 1) {
        if (t < s) {
            float v = rv[t + s]; int j = ri[t + s];
            if (v > rv[t] || (v == rv[t] && j < ri[t])) { rv[t] = v; ri[t] = j; }
            float v2 = rv2[t + s]; int j2 = ri2[t + s];
            if (v2 < rv2[t] || (v2 == rv2[t] && j2 < ri2[t])) { rv2[t] = v2; ri2[t] = j2; }
        }
        __syncthreads();
    }

    if (t == 0) {
        s_jp = ri[0];
        s_jn = ri2[0];
        s_dp = rv[0];
        s_dn = rv2[0];
        s_valid = (rv[0] != -1e30f) && (rv2[0] != 1e30f);
    }
    __syncthreads();

    // ---- dist_unc numerators for the two selected pairs + u row sum ----
    const int jp = s_jp;
    const int jn = s_jn;
    float dp_ = ei[t] - emb[(size_t)jp * D + t];
    float dn_ = ei[t] - emb[(size_t)jn * D + t];
    rv[t]  = wi[t] * dp_ * dp_;
    rv2[t] = wi[t] * dn_ * dn_;
    ru[t]  = u;
    __syncthreads();
    for (int s = 128; s > 0; s >>= 1) {
        if (t < s) {
            rv[t]  += rv[t + s];
            rv2[t] += rv2[t + s];
            ru[t]  += ru[t + s];
        }
        __syncthreads();
    }

    if (t == 0) {
        atomicAdd(acc + 2, ru[0]);
        if (s_valid) {
            float dp = s_dp, dn = s_dn;
            float up = sqrtf(rv[0]  / (dp * dp) + EPS);
            float un = sqrtf(rv2[0] / (dn * dn) + EPS);
            float sigma = sqrtf(up * up + un * un + EPS);
            float margin_eff = MARGIN + UW * sigma;
            float z = (dp - dn + margin_eff) / sigma;   // TEMPERATURE = 1
            float sp = fmaxf(z, 0.f) + log1pf(expf(-fabsf(z)));  // stable softplus
            atomicAdd(acc + 0, sigma * sp);
            atomicAdd(acc + 1, 1.0f);
        }
    }
}

__global__ void triplet_finalize(const float* __restrict__ acc, float* __restrict__ out) {
    if (threadIdx.x == 0) {
        float n_valid = fmaxf(acc[1], 1.0f);
        float total = acc[0] / n_valid + UW * (acc[2] / (float)(B * D));
        if (!isfinite(total)) total = 0.f;
        out[0] = total;
    }
}

extern "C" void kernel_launch(void* const* d_in, const int* in_sizes, int n_in,
                              void* d_out, int out_size, void* d_ws, size_t ws_size,
                              hipStream_t stream) {
    const float* emb = (const float*)d_in[0];
    const float* unc = (const float*)d_in[1];
    const int* labels = (const int*)d_in[2];
    float* out = (float*)d_out;
    float* acc = (float*)d_ws;

    hipMemsetAsync(acc, 0, 3 * sizeof(float), stream);
    triplet_main<<<B, 256, 0, stream>>>(emb, unc, labels, acc);
    triplet_finalize<<<1, 64, 0, stream>>>(acc, out);
}

// Round 2
// 101.547 us; speedup vs baseline: 1.0249x; 1.0249x over previous
//
#include <hip/hip_runtime.h>
#include <math.h>

#define B 512
#define D 256
#define MARGIN 0.3f
#define UW 0.05f
#define MIN_U 1e-6f
#define EPS 1e-8f

#define TI 16   // anchor rows per block
#define TJ 64   // candidate cols per block
#define BK 64   // k-chunk

// ws layout:
//   [0,    4096) u64 pmax[512]   (memset 0)
//   [4096, 4108) float acc[3]    (memset 0)  0=loss_sum 1=n_valid 2=u_sum
//   [4112, 4116) u32 counter     (memset 0)
//   [4224, 8320) u64 nmin[512]   (memset 0xFF)

static __device__ inline unsigned long long shfl_xor_u64_w16(unsigned long long v, int m) {
    unsigned int lo = (unsigned int)v;
    unsigned int hi = (unsigned int)(v >> 32);
    lo = __shfl_xor(lo, m, 16);
    hi = __shfl_xor(hi, m, 16);
    return ((unsigned long long)hi << 32) | lo;
}

__global__ __launch_bounds__(256) void dist_mine(const float* __restrict__ emb,
                                                 const int* __restrict__ labels,
                                                 unsigned long long* __restrict__ pmax,
                                                 unsigned long long* __restrict__ nmin) {
    const int jt = blockIdx.x;   // 0..7   (j tile of 64)
    const int it = blockIdx.y;   // 0..31  (i tile of 16)
    const int t  = threadIdx.x;  // 0..255
    const int row  = t >> 4;     // i within tile, 0..15
    const int col4 = (t & 15) * 4;

    __shared__ float As[BK][TI + 1];   // [k][i]
    __shared__ float Bs[BK][TJ + 4];   // [k][j], stride 68 keeps float4 16B-aligned
    __shared__ int labI[TI], labJ[TJ];

    const int gi0 = it * TI;
    const int gj0 = jt * TJ;
    if (t < TI) labI[t] = labels[gi0 + t];
    if (t < TJ) labJ[t] = labels[gj0 + t];

    float a0 = 0.f, a1 = 0.f, a2 = 0.f, a3 = 0.f;

    for (int kc = 0; kc < D; kc += BK) {
        __syncthreads();
        // stage A tile: 16 rows x 64 k = 256 float4, 1 per thread (coalesced)
        {
            const int r = t >> 4;
            const int f = t & 15;
            float4 v = *reinterpret_cast<const float4*>(&emb[(size_t)(gi0 + r) * D + kc + f * 4]);
            As[f * 4 + 0][r] = v.x;
            As[f * 4 + 1][r] = v.y;
            As[f * 4 + 2][r] = v.z;
            As[f * 4 + 3][r] = v.w;
        }
        // stage B tile: 64 rows x 64 k = 1024 float4, 4 per thread (coalesced)
#pragma unroll
        for (int g = 0; g < 4; ++g) {
            const int r = g * 16 + (t >> 4);
            const int f = t & 15;
            float4 v = *reinterpret_cast<const float4*>(&emb[(size_t)(gj0 + r) * D + kc + f * 4]);
            Bs[f * 4 + 0][r] = v.x;
            Bs[f * 4 + 1][r] = v.y;
            Bs[f * 4 + 2][r] = v.z;
            Bs[f * 4 + 3][r] = v.w;
        }
        __syncthreads();
#pragma unroll 8
        for (int k = 0; k < BK; ++k) {
            float a = As[k][row];
            float4 b = *reinterpret_cast<const float4*>(&Bs[k][col4]);
            float d;
            d = a - b.x; a0 = fmaf(d, d, a0);
            d = a - b.y; a1 = fmaf(d, d, a1);
            d = a - b.z; a2 = fmaf(d, d, a2);
            d = a - b.w; a3 = fmaf(d, d, a3);
        }
    }

    // ---- masked mining for this thread's 4 candidates ----
    const int gi = gi0 + row;
    const int li = labI[row];
    unsigned long long pbest = 0ull;
    unsigned long long nbest = ~0ull;
    float accs[4] = {a0, a1, a2, a3};
#pragma unroll
    for (int c = 0; c < 4; ++c) {
        const int jj = col4 + c;
        const int gj = gj0 + jj;
        const float dist = sqrtf(accs[c]) + EPS;
        const int lj = labJ[jj];
        const unsigned long long fb = (unsigned long long)__float_as_uint(dist) << 32;
        if (li == lj && gi != gj) {
            unsigned long long e = fb | (unsigned int)(0xFFFFFFFFu - (unsigned int)gj);
            pbest = pbest > e ? pbest : e;   // larger dist wins; tie -> smaller j
        }
        if (li != lj) {
            unsigned long long e = fb | (unsigned int)gj;
            nbest = nbest < e ? nbest : e;   // smaller dist wins; tie -> smaller j
        }
    }
    // reduce across the 16 consecutive lanes that share this row
#pragma unroll
    for (int m = 1; m < 16; m <<= 1) {
        unsigned long long p2 = shfl_xor_u64_w16(pbest, m);
        unsigned long long n2 = shfl_xor_u64_w16(nbest, m);
        pbest = pbest > p2 ? pbest : p2;
        nbest = nbest < n2 ? nbest : n2;
    }
    if ((t & 15) == 0) {
        if (pbest != 0ull)  atomicMax(&pmax[gi], pbest);
        if (nbest != ~0ull) atomicMin(&nmin[gi], nbest);
    }
}

__global__ __launch_bounds__(256) void finalize(const float* __restrict__ emb,
                                                const float* __restrict__ unc,
                                                const unsigned long long* __restrict__ pmax,
                                                const unsigned long long* __restrict__ nmin,
                                                float* __restrict__ acc,
                                                unsigned int* __restrict__ counter,
                                                float* __restrict__ out) {
    const int i = blockIdx.x;
    const int t = threadIdx.x;
    __shared__ float r0[256], r1[256], r2[256];

    const unsigned long long pe = pmax[i];
    const unsigned long long ne = nmin[i];
    const bool valid = (pe != 0ull) && (ne != ~0ull);
    const int jp = valid ? (int)(0xFFFFFFFFu - (unsigned int)pe) : i;
    const int jn = valid ? (int)(unsigned int)ne : i;
    const float dp = __uint_as_float((unsigned int)(pe >> 32));
    const float dn = __uint_as_float((unsigned int)(ne >> 32));

    float u = unc[(size_t)i * D + t];
    u = fminf(fmaxf(u, MIN_U), 1.0f);
    if (!isfinite(u)) u = MIN_U;
    const float w = u * u;
    const float ei = emb[(size_t)i * D + t];
    const float d1 = ei - emb[(size_t)jp * D + t];
    const float d2 = ei - emb[(size_t)jn * D + t];

    r0[t] = w * d1 * d1;
    r1[t] = w * d2 * d2;
    r2[t] = u;
    __syncthreads();
    for (int s = 128; s > 0; s >>= 1) {
        if (t < s) {
            r0[t] += r0[t + s];
            r1[t] += r1[t + s];
            r2[t] += r2[t + s];
        }
        __syncthreads();
    }

    if (t == 0) {
        atomicAdd(&acc[2], r2[0]);
        if (valid) {
            const float up2 = r0[0] / (dp * dp) + EPS;   // = u_pos^2
            const float un2 = r1[0] / (dn * dn) + EPS;   // = u_neg^2
            const float sigma = sqrtf(up2 + un2 + EPS);
            const float z = (dp - dn + MARGIN + UW * sigma) / sigma;  // TEMPERATURE=1
            const float sp = fmaxf(z, 0.f) + log1pf(expf(-fabsf(z)));
            atomicAdd(&acc[0], sigma * sp);
            atomicAdd(&acc[1], 1.0f);
        }
        __threadfence();
        const unsigned int done = atomicAdd(counter, 1u);
        if (done == (unsigned int)(B - 1)) {
            const float ls = atomicAdd(&acc[0], 0.0f);
            const float nv = atomicAdd(&acc[1], 0.0f);
            const float us = atomicAdd(&acc[2], 0.0f);
            float total = ls / fmaxf(nv, 1.0f) + UW * (us / (float)(B * D));
            if (!isfinite(total)) total = 0.f;
            out[0] = total;
        }
    }
}

extern "C" void kernel_launch(void* const* d_in, const int* in_sizes, int n_in,
                              void* d_out, int out_size, void* d_ws, size_t ws_size,
                              hipStream_t stream) {
    const float* emb = (const float*)d_in[0];
    const float* unc = (const float*)d_in[1];
    const int* labels = (const int*)d_in[2];
    float* out = (float*)d_out;

    char* ws = (char*)d_ws;
    unsigned long long* pmax = (unsigned long long*)(ws);
    float* acc = (float*)(ws + 4096);
    unsigned int* counter = (unsigned int*)(ws + 4112);
    unsigned long long* nmin = (unsigned long long*)(ws + 4224);

    hipMemsetAsync(ws, 0, 4224, stream);
    hipMemsetAsync(ws + 4224, 0xFF, 4096, stream);

    dim3 grid(B / TJ, B / TI);   // (8, 32)
    dist_mine<<<grid, 256, 0, stream>>>(emb, labels, pmax, nmin);
    finalize<<<B, 256, 0, stream>>>(emb, unc, pmax, nmin, acc, counter, out);
}

// Round 3
// 74.736 us; speedup vs baseline: 1.3926x; 1.3587x over previous
//
#include <hip/hip_runtime.h>
#include <math.h>

#define B 512
#define D 256
#define MARGIN 0.3f
#define UW 0.05f
#define MIN_U 1e-6f
#define EPS 1e-8f

#define TI 16   // anchor rows per block
#define TJ 64   // candidate cols per block
#define BK 64   // k-chunk
#define NJT (B / TJ)   // 8 j-tiles

typedef unsigned long long ull;

// ws layout (no init required -- every slot written before read):
//   [0,      32768)  ull pmax_part[NJT][B]
//   [32768,  65536)  ull nmin_part[NJT][B]
//   [65536,  66304)  float blk_part[64][3]  (loss_sum, n_valid, u_sum)

static __device__ inline ull shfl_xor_u64(ull v, int m) {
    unsigned int lo = (unsigned int)v;
    unsigned int hi = (unsigned int)(v >> 32);
    lo = __shfl_xor(lo, m, 64);
    hi = __shfl_xor(hi, m, 64);
    return ((ull)hi << 32) | lo;
}

__global__ __launch_bounds__(256) void dist_mine(const float* __restrict__ emb,
                                                 const int* __restrict__ labels,
                                                 ull* __restrict__ pmax_part,
                                                 ull* __restrict__ nmin_part) {
    const int jt = blockIdx.x;   // 0..7
    const int it = blockIdx.y;   // 0..31
    const int t  = threadIdx.x;
    const int row  = t >> 4;
    const int col4 = (t & 15) * 4;

    __shared__ float As[BK][TI + 1];
    __shared__ float Bs[BK][TJ + 4];
    __shared__ int labI[TI], labJ[TJ];

    const int gi0 = it * TI;
    const int gj0 = jt * TJ;
    if (t < TI) labI[t] = labels[gi0 + t];
    if (t < TJ) labJ[t] = labels[gj0 + t];

    float a0 = 0.f, a1 = 0.f, a2 = 0.f, a3 = 0.f;

    for (int kc = 0; kc < D; kc += BK) {
        __syncthreads();
        {
            const int r = t >> 4;
            const int f = t & 15;
            float4 v = *reinterpret_cast<const float4*>(&emb[(size_t)(gi0 + r) * D + kc + f * 4]);
            As[f * 4 + 0][r] = v.x;
            As[f * 4 + 1][r] = v.y;
            As[f * 4 + 2][r] = v.z;
            As[f * 4 + 3][r] = v.w;
        }
#pragma unroll
        for (int g = 0; g < 4; ++g) {
            const int r = g * 16 + (t >> 4);
            const int f = t & 15;
            float4 v = *reinterpret_cast<const float4*>(&emb[(size_t)(gj0 + r) * D + kc + f * 4]);
            Bs[f * 4 + 0][r] = v.x;
            Bs[f * 4 + 1][r] = v.y;
            Bs[f * 4 + 2][r] = v.z;
            Bs[f * 4 + 3][r] = v.w;
        }
        __syncthreads();
#pragma unroll 8
        for (int k = 0; k < BK; ++k) {
            float a = As[k][row];
            float4 b = *reinterpret_cast<const float4*>(&Bs[k][col4]);
            float d;
            d = a - b.x; a0 = fmaf(d, d, a0);
            d = a - b.y; a1 = fmaf(d, d, a1);
            d = a - b.z; a2 = fmaf(d, d, a2);
            d = a - b.w; a3 = fmaf(d, d, a3);
        }
    }

    const int gi = gi0 + row;
    const int li = labI[row];
    ull pbest = 0ull;
    ull nbest = ~0ull;
    float accs[4] = {a0, a1, a2, a3};
#pragma unroll
    for (int c = 0; c < 4; ++c) {
        const int jj = col4 + c;
        const int gj = gj0 + jj;
        const float dist = sqrtf(accs[c]) + EPS;
        const int lj = labJ[jj];
        const ull fb = (ull)__float_as_uint(dist) << 32;
        if (li == lj && gi != gj) {
            ull e = fb | (unsigned int)(0xFFFFFFFFu - (unsigned int)gj);
            pbest = pbest > e ? pbest : e;   // larger dist wins; tie -> smaller j
        }
        if (li != lj) {
            ull e = fb | (unsigned int)gj;
            nbest = nbest < e ? nbest : e;   // smaller dist wins; tie -> smaller j
        }
    }
    // reduce across the 16 consecutive lanes sharing this row (xor stays in group)
#pragma unroll
    for (int m = 1; m < 16; m <<= 1) {
        ull p2 = shfl_xor_u64(pbest, m);
        ull n2 = shfl_xor_u64(nbest, m);
        pbest = pbest > p2 ? pbest : p2;
        nbest = nbest < n2 ? nbest : n2;
    }
    if ((t & 15) == 0) {
        pmax_part[(size_t)jt * B + gi] = pbest;
        nmin_part[(size_t)jt * B + gi] = nbest;
    }
}

// 64 blocks x 256 threads; each wave handles 2 anchors (64*4*2 = 512)
__global__ __launch_bounds__(256) void finalize_part(const float* __restrict__ emb,
                                                     const float* __restrict__ unc,
                                                     const ull* __restrict__ pmax_part,
                                                     const ull* __restrict__ nmin_part,
                                                     float* __restrict__ blk_part) {
    const int t = threadIdx.x;
    const int wave = t >> 6;   // 0..3
    const int lane = t & 63;
    __shared__ float red[4][3];

    float loss_sum = 0.f, nval = 0.f, usum = 0.f;
    const float4* emb4 = reinterpret_cast<const float4*>(emb);
    const float4* unc4 = reinterpret_cast<const float4*>(unc);

#pragma unroll
    for (int a = 0; a < 2; ++a) {
        const int i = blockIdx.x * 8 + wave * 2 + a;

        // reduce the 8 per-jt partials (lanes 0..7 carry real data)
        ull pe = 0ull, ne = ~0ull;
        if (lane < NJT) {
            pe = pmax_part[(size_t)lane * B + i];
            ne = nmin_part[(size_t)lane * B + i];
        }
#pragma unroll
        for (int m = 1; m < NJT; m <<= 1) {
            ull p2 = shfl_xor_u64(pe, m);
            ull n2 = shfl_xor_u64(ne, m);
            pe = pe > p2 ? pe : p2;
            ne = ne < n2 ? ne : n2;
        }
        pe = shfl_xor_u64(pe, 0) , pe = ((ull)(unsigned int)__shfl((int)(pe >> 32), 0, 64) << 32) | (unsigned int)__shfl((int)(unsigned int)pe, 0, 64);
        ne = ((ull)(unsigned int)__shfl((int)(ne >> 32), 0, 64) << 32) | (unsigned int)__shfl((int)(unsigned int)ne, 0, 64);

        const bool valid = (pe != 0ull) && (ne != ~0ull);
        const int jp = valid ? (int)(0xFFFFFFFFu - (unsigned int)pe) : i;
        const int jn = valid ? (int)(unsigned int)ne : i;
        const float dp = __uint_as_float((unsigned int)(pe >> 32));
        const float dn = __uint_as_float((unsigned int)(ne >> 32));

        // coalesced float4 row reads: lane l covers dims 4l..4l+3
        float4 e = emb4[(size_t)i * 64 + lane];
        float4 u = unc4[(size_t)i * 64 + lane];
        float4 p = emb4[(size_t)jp * 64 + lane];
        float4 n = emb4[(size_t)jn * 64 + lane];
        float ux = fminf(fmaxf(u.x, MIN_U), 1.0f);
        float uy = fminf(fmaxf(u.y, MIN_U), 1.0f);
        float uz = fminf(fmaxf(u.z, MIN_U), 1.0f);
        float uw_ = fminf(fmaxf(u.w, MIN_U), 1.0f);

        float s0, s1, s2, d;
        d = e.x - p.x; s0 = ux * ux * d * d;
        d = e.y - p.y; s0 = fmaf(uy * uy, d * d, s0);
        d = e.z - p.z; s0 = fmaf(uz * uz, d * d, s0);
        d = e.w - p.w; s0 = fmaf(uw_ * uw_, d * d, s0);
        d = e.x - n.x; s1 = ux * ux * d * d;
        d = e.y - n.y; s1 = fmaf(uy * uy, d * d, s1);
        d = e.z - n.z; s1 = fmaf(uz * uz, d * d, s1);
        d = e.w - n.w; s1 = fmaf(uw_ * uw_, d * d, s1);
        s2 = ux + uy + uz + uw_;

#pragma unroll
        for (int m = 1; m < 64; m <<= 1) {
            s0 += __shfl_xor(s0, m, 64);
            s1 += __shfl_xor(s1, m, 64);
            s2 += __shfl_xor(s2, m, 64);
        }

        if (lane == 0) {
            usum += s2;
            if (valid) {
                const float up2 = s0 / (dp * dp) + EPS;
                const float un2 = s1 / (dn * dn) + EPS;
                const float sigma = sqrtf(up2 + un2 + EPS);
                const float z = (dp - dn + MARGIN + UW * sigma) / sigma;  // T=1
                const float sp = fmaxf(z, 0.f) + log1pf(expf(-fabsf(z)));
                loss_sum += sigma * sp;
                nval += 1.0f;
            }
        }
    }

    if (lane == 0) {
        red[wave][0] = loss_sum;
        red[wave][1] = nval;
        red[wave][2] = usum;
    }
    __syncthreads();
    if (t == 0) {
        float l = red[0][0] + red[1][0] + red[2][0] + red[3][0];
        float v = red[0][1] + red[1][1] + red[2][1] + red[3][1];
        float s = red[0][2] + red[1][2] + red[2][2] + red[3][2];
        blk_part[blockIdx.x * 3 + 0] = l;
        blk_part[blockIdx.x * 3 + 1] = v;
        blk_part[blockIdx.x * 3 + 2] = s;
    }
}

__global__ void reduce_out(const float* __restrict__ blk_part, float* __restrict__ out) {
    const int lane = threadIdx.x;   // 64 threads
    float l = blk_part[lane * 3 + 0];
    float v = blk_part[lane * 3 + 1];
    float s = blk_part[lane * 3 + 2];
#pragma unroll
    for (int m = 1; m < 64; m <<= 1) {
        l += __shfl_xor(l, m, 64);
        v += __shfl_xor(v, m, 64);
        s += __shfl_xor(s, m, 64);
    }
    if (lane == 0) {
        float total = l / fmaxf(v, 1.0f) + UW * (s / (float)(B * D));
        if (!isfinite(total)) total = 0.f;
        out[0] = total;
    }
}

extern "C" void kernel_launch(void* const* d_in, const int* in_sizes, int n_in,
                              void* d_out, int out_size, void* d_ws, size_t ws_size,
                              hipStream_t stream) {
    const float* emb = (const float*)d_in[0];
    const float* unc = (const float*)d_in[1];
    const int* labels = (const int*)d_in[2];
    float* out = (float*)d_out;

    char* ws = (char*)d_ws;
    ull* pmax_part = (ull*)(ws);
    ull* nmin_part = (ull*)(ws + 32768);
    float* blk_part = (float*)(ws + 65536);

    dim3 grid(NJT, B / TI);   // (8, 32)
    dist_mine<<<grid, 256, 0, stream>>>(emb, labels, pmax_part, nmin_part);
    finalize_part<<<64, 256, 0, stream>>>(emb, unc, pmax_part, nmin_part, blk_part);
    reduce_out<<<1, 64, 0, stream>>>(blk_part, out);
}

// Round 4
// 71.913 us; speedup vs baseline: 1.4473x; 1.0392x over previous
//
#include <hip/hip_runtime.h>
#include <math.h>

#define B 512
#define D 256
#define MARGIN 0.3f
#define UW 0.05f
#define MIN_U 1e-6f
#define EPS 1e-8f

#define TI 16   // anchor rows per block
#define TJ 64   // candidate cols per block
#define BK 64   // k-chunk
#define NJT (B / TJ)   // 8 j-tiles

typedef unsigned long long ull;

// ws layout (no init required -- every slot written before read):
//   [0,      32768)  ull pmax_part[NJT][B]
//   [32768,  65536)  ull nmin_part[NJT][B]
//   [65536,  66304)  float blk_part[64][3]  (loss_sum, n_valid, u_sum)
//   [66304,  66308)  u32 counter   (zeroed by dist_mine block (0,0))

static __device__ inline ull shfl_xor_u64(ull v, int m) {
    unsigned int lo = (unsigned int)v;
    unsigned int hi = (unsigned int)(v >> 32);
    lo = __shfl_xor(lo, m, 64);
    hi = __shfl_xor(hi, m, 64);
    return ((ull)hi << 32) | lo;
}

static __device__ inline ull bcast_u64_lane0(ull v) {
    unsigned int lo = (unsigned int)v;
    unsigned int hi = (unsigned int)(v >> 32);
    lo = (unsigned int)__shfl((int)lo, 0, 64);
    hi = (unsigned int)__shfl((int)hi, 0, 64);
    return ((ull)hi << 32) | lo;
}

__global__ __launch_bounds__(256) void dist_mine(const float* __restrict__ emb,
                                                 const int* __restrict__ labels,
                                                 ull* __restrict__ pmax_part,
                                                 ull* __restrict__ nmin_part,
                                                 unsigned int* __restrict__ counter) {
    const int jt = blockIdx.x;   // 0..7
    const int it = blockIdx.y;   // 0..31
    const int t  = threadIdx.x;
    const int row  = t >> 4;
    const int col4 = (t & 15) * 4;

    if (jt == 0 && it == 0 && t == 0) *counter = 0u;  // init for finalize kernel

    __shared__ float As[BK][TI + 1];
    __shared__ float Bs[BK][TJ + 4];
    __shared__ int labI[TI], labJ[TJ];

    const int gi0 = it * TI;
    const int gj0 = jt * TJ;
    if (t < TI) labI[t] = labels[gi0 + t];
    if (t < TJ) labJ[t] = labels[gj0 + t];

    float a0 = 0.f, a1 = 0.f, a2 = 0.f, a3 = 0.f;

    for (int kc = 0; kc < D; kc += BK) {
        __syncthreads();
        {
            const int r = t >> 4;
            const int f = t & 15;
            float4 v = *reinterpret_cast<const float4*>(&emb[(size_t)(gi0 + r) * D + kc + f * 4]);
            As[f * 4 + 0][r] = v.x;
            As[f * 4 + 1][r] = v.y;
            As[f * 4 + 2][r] = v.z;
            As[f * 4 + 3][r] = v.w;
        }
#pragma unroll
        for (int g = 0; g < 4; ++g) {
            const int r = g * 16 + (t >> 4);
            const int f = t & 15;
            float4 v = *reinterpret_cast<const float4*>(&emb[(size_t)(gj0 + r) * D + kc + f * 4]);
            Bs[f * 4 + 0][r] = v.x;
            Bs[f * 4 + 1][r] = v.y;
            Bs[f * 4 + 2][r] = v.z;
            Bs[f * 4 + 3][r] = v.w;
        }
        __syncthreads();
#pragma unroll 8
        for (int k = 0; k < BK; ++k) {
            float a = As[k][row];
            float4 b = *reinterpret_cast<const float4*>(&Bs[k][col4]);
            float d;
            d = a - b.x; a0 = fmaf(d, d, a0);
            d = a - b.y; a1 = fmaf(d, d, a1);
            d = a - b.z; a2 = fmaf(d, d, a2);
            d = a - b.w; a3 = fmaf(d, d, a3);
        }
    }

    const int gi = gi0 + row;
    const int li = labI[row];
    ull pbest = 0ull;
    ull nbest = ~0ull;
    float accs[4] = {a0, a1, a2, a3};
#pragma unroll
    for (int c = 0; c < 4; ++c) {
        const int jj = col4 + c;
        const int gj = gj0 + jj;
        const float dist = sqrtf(accs[c]) + EPS;
        const int lj = labJ[jj];
        const ull fb = (ull)__float_as_uint(dist) << 32;
        if (li == lj && gi != gj) {
            ull e = fb | (unsigned int)(0xFFFFFFFFu - (unsigned int)gj);
            pbest = pbest > e ? pbest : e;   // larger dist wins; tie -> smaller j
        }
        if (li != lj) {
            ull e = fb | (unsigned int)gj;
            nbest = nbest < e ? nbest : e;   // smaller dist wins; tie -> smaller j
        }
    }
    // reduce across the 16 consecutive lanes sharing this row (xor stays in group)
#pragma unroll
    for (int m = 1; m < 16; m <<= 1) {
        ull p2 = shfl_xor_u64(pbest, m);
        ull n2 = shfl_xor_u64(nbest, m);
        pbest = pbest > p2 ? pbest : p2;
        nbest = nbest < n2 ? nbest : n2;
    }
    if ((t & 15) == 0) {
        pmax_part[(size_t)jt * B + gi] = pbest;
        nmin_part[(size_t)jt * B + gi] = nbest;
    }
}

// 64 blocks x 256 threads; each wave handles 2 anchors (64 blk * 4 waves * 2 = 512).
// Last-done block reduces the 64 per-block partials and writes out[0].
__global__ __launch_bounds__(256) void finalize(const float* __restrict__ emb,
                                                const float* __restrict__ unc,
                                                const ull* __restrict__ pmax_part,
                                                const ull* __restrict__ nmin_part,
                                                float* __restrict__ blk_part,
                                                unsigned int* __restrict__ counter,
                                                float* __restrict__ out) {
    const int t = threadIdx.x;
    const int wave = t >> 6;   // 0..3
    const int lane = t & 63;
    __shared__ float red[4][3];
    __shared__ int s_last;

    float loss_sum = 0.f, nval = 0.f, usum = 0.f;
    const float4* emb4 = reinterpret_cast<const float4*>(emb);
    const float4* unc4 = reinterpret_cast<const float4*>(unc);

#pragma unroll
    for (int a = 0; a < 2; ++a) {
        const int i = blockIdx.x * 8 + wave * 2 + a;

        // reduce the 8 per-jt partials (lanes 0..7 carry real data)
        ull pe = 0ull, ne = ~0ull;
        if (lane < NJT) {
            pe = pmax_part[(size_t)lane * B + i];
            ne = nmin_part[(size_t)lane * B + i];
        }
#pragma unroll
        for (int m = 1; m < NJT; m <<= 1) {
            ull p2 = shfl_xor_u64(pe, m);
            ull n2 = shfl_xor_u64(ne, m);
            pe = pe > p2 ? pe : p2;
            ne = ne < n2 ? ne : n2;
        }
        pe = bcast_u64_lane0(pe);
        ne = bcast_u64_lane0(ne);

        const bool valid = (pe != 0ull) && (ne != ~0ull);
        const int jp = valid ? (int)(0xFFFFFFFFu - (unsigned int)pe) : i;
        const int jn = valid ? (int)(unsigned int)ne : i;
        const float dp = __uint_as_float((unsigned int)(pe >> 32));
        const float dn = __uint_as_float((unsigned int)(ne >> 32));

        // coalesced float4 row reads: lane l covers dims 4l..4l+3
        float4 e = emb4[(size_t)i * 64 + lane];
        float4 u = unc4[(size_t)i * 64 + lane];
        float4 p = emb4[(size_t)jp * 64 + lane];
        float4 n = emb4[(size_t)jn * 64 + lane];
        float ux = fminf(fmaxf(u.x, MIN_U), 1.0f);
        float uy = fminf(fmaxf(u.y, MIN_U), 1.0f);
        float uz = fminf(fmaxf(u.z, MIN_U), 1.0f);
        float uw_ = fminf(fmaxf(u.w, MIN_U), 1.0f);

        float s0, s1, s2, d;
        d = e.x - p.x; s0 = ux * ux * d * d;
        d = e.y - p.y; s0 = fmaf(uy * uy, d * d, s0);
        d = e.z - p.z; s0 = fmaf(uz * uz, d * d, s0);
        d = e.w - p.w; s0 = fmaf(uw_ * uw_, d * d, s0);
        d = e.x - n.x; s1 = ux * ux * d * d;
        d = e.y - n.y; s1 = fmaf(uy * uy, d * d, s1);
        d = e.z - n.z; s1 = fmaf(uz * uz, d * d, s1);
        d = e.w - n.w; s1 = fmaf(uw_ * uw_, d * d, s1);
        s2 = ux + uy + uz + uw_;

#pragma unroll
        for (int m = 1; m < 64; m <<= 1) {
            s0 += __shfl_xor(s0, m, 64);
            s1 += __shfl_xor(s1, m, 64);
            s2 += __shfl_xor(s2, m, 64);
        }

        if (lane == 0) {
            usum += s2;
            if (valid) {
                const float up2 = s0 / (dp * dp) + EPS;
                const float un2 = s1 / (dn * dn) + EPS;
                const float sigma = sqrtf(up2 + un2 + EPS);
                const float z = (dp - dn + MARGIN + UW * sigma) / sigma;  // T=1
                const float sp = fmaxf(z, 0.f) + log1pf(expf(-fabsf(z)));
                loss_sum += sigma * sp;
                nval += 1.0f;
            }
        }
    }

    if (lane == 0) {
        red[wave][0] = loss_sum;
        red[wave][1] = nval;
        red[wave][2] = usum;
    }
    __syncthreads();
    if (t == 0) {
        // device-scope release stores of this block's partials
        float l = red[0][0] + red[1][0] + red[2][0] + red[3][0];
        float v = red[0][1] + red[1][1] + red[2][1] + red[3][1];
        float s = red[0][2] + red[1][2] + red[2][2] + red[3][2];
        __hip_atomic_store(&blk_part[blockIdx.x * 3 + 0], l, __ATOMIC_RELAXED, __HIP_MEMORY_SCOPE_AGENT);
        __hip_atomic_store(&blk_part[blockIdx.x * 3 + 1], v, __ATOMIC_RELAXED, __HIP_MEMORY_SCOPE_AGENT);
        __hip_atomic_store(&blk_part[blockIdx.x * 3 + 2], s, __ATOMIC_RELAXED, __HIP_MEMORY_SCOPE_AGENT);
        unsigned int done = __hip_atomic_fetch_add(counter, 1u, __ATOMIC_ACQ_REL, __HIP_MEMORY_SCOPE_AGENT);
        s_last = (done == 63u);
    }
    __syncthreads();

    if (s_last && wave == 0) {
        // last block: reduce the 64 per-block partials
        float l = __hip_atomic_load(&blk_part[lane * 3 + 0], __ATOMIC_RELAXED, __HIP_MEMORY_SCOPE_AGENT);
        float v = __hip_atomic_load(&blk_part[lane * 3 + 1], __ATOMIC_RELAXED, __HIP_MEMORY_SCOPE_AGENT);
        float s = __hip_atomic_load(&blk_part[lane * 3 + 2], __ATOMIC_RELAXED, __HIP_MEMORY_SCOPE_AGENT);
#pragma unroll
        for (int m = 1; m < 64; m <<= 1) {
            l += __shfl_xor(l, m, 64);
            v += __shfl_xor(v, m, 64);
            s += __shfl_xor(s, m, 64);
        }
        if (lane == 0) {
            float total = l / fmaxf(v, 1.0f) + UW * (s / (float)(B * D));
            if (!isfinite(total)) total = 0.f;
            out[0] = total;
        }
    }
}

extern "C" void kernel_launch(void* const* d_in, const int* in_sizes, int n_in,
                              void* d_out, int out_size, void* d_ws, size_t ws_size,
                              hipStream_t stream) {
    const float* emb = (const float*)d_in[0];
    const float* unc = (const float*)d_in[1];
    const int* labels = (const int*)d_in[2];
    float* out = (float*)d_out;

    char* ws = (char*)d_ws;
    ull* pmax_part = (ull*)(ws);
    ull* nmin_part = (ull*)(ws + 32768);
    float* blk_part = (float*)(ws + 65536);
    unsigned int* counter = (unsigned int*)(ws + 66304);

    dim3 grid(NJT, B / TI);   // (8, 32)
    dist_mine<<<grid, 256, 0, stream>>>(emb, labels, pmax_part, nmin_part, counter);
    finalize<<<64, 256, 0, stream>>>(emb, unc, pmax_part, nmin_part, blk_part, counter, out);
}